// Round 3
// baseline (387.155 us; speedup 1.0000x reference)
//
#include <hip/hip_runtime.h>
#include <hip/hip_bf16.h>

// Problem constants
#define B_  2
#define S_  2048
#define D_  1024
#define H_  16
#define HD_ 64
#define M_  4096   // B_*S_

// Inputs/outputs f32; internal compute bf16 MFMA with f32 accumulation.
// ws (32 MB + 12 KB):
//   [0,8)MB  q bf16 (CE-prescaled via WTq/biasf; attn in-place)
//   [8,16)MB kb bf16
//   [16,24)MB WT bf16: 4 x [1024][1024] ([q CE*g | k g | v g | o plain])
//   [24,32)MB xhat bf16 [4096][1024]  (LN(data), affine folded into WT/biasf)
//   +32MB: biasf f32[3][1024]
// d_out (16 MB f32) as scratch until the final GEMM:
//   [0,8)MB vT bf16 [bh][d][s]   [8,16)MB kT bf16 [bh][d][s]
//
// attn_fused (this round): 64 q-cols per wave -> each LDS A-frag read
// feeds 2 MFMAs (halves LDS read traffic, the R2 bottleneck: ~57% LDS
// busy per CU). Grid (64,16), 4 waves; wave w = kt-QUARTER (32 kt of a
// 128-kt superstep) x all 64 q. Staging layout identical to R2 (glds,
// pre-swizzled global source). Epilogue combines 4 partials in two
// 32KB LDS chunks; conversion work split across waves (unit = w).

typedef __attribute__((ext_vector_type(8))) short short8;
typedef __attribute__((ext_vector_type(4))) float f32x4;
typedef __attribute__((ext_vector_type(2))) float f32x2;
typedef __attribute__((ext_vector_type(16))) float f32x16;

#define CE_ 0.1803368801111204f   // 0.125 * log2(e)

typedef __attribute__((address_space(1))) const unsigned GU;
typedef __attribute__((address_space(3))) unsigned LU;
static __device__ __forceinline__ void glds16(const void* g, void* l){
  __builtin_amdgcn_global_load_lds((GU*)g, (LU*)l, 16, 0, 0);
}

static __device__ __forceinline__ unsigned short f2bfc(float f){
  union{float f; unsigned u;} c; c.f = f;
  return (unsigned short)((c.u + 0x8000u) >> 16);
}
static __device__ __forceinline__ unsigned pk2bf(float a, float b){
  union{float f; unsigned u;} ca, cb; ca.f=a; cb.f=b;
  return __builtin_amdgcn_perm(cb.u + 0x8000u, ca.u + 0x8000u, 0x07060302u);
}
static __device__ __forceinline__ unsigned pk2bft(float a, float b){
  union{float f; unsigned u;} ca, cb; ca.f=a; cb.f=b;
  return __builtin_amdgcn_perm(cb.u, ca.u, 0x07060302u);
}
static __device__ __forceinline__ short8 mk8(unsigned x0, unsigned x1,
                                             unsigned x2, unsigned x3){
  union{ unsigned u[4]; short8 s; } t;
  t.u[0]=x0; t.u[1]=x1; t.u[2]=x2; t.u[3]=x3; return t.s;
}
// v_permlane32_swap_b32: new_x[32:63] = old_y[0:31]; new_y[0:31] = old_x[32:63]
static __device__ __forceinline__ void plswap(unsigned &x, unsigned &y){
  auto r = __builtin_amdgcn_permlane32_swap(x, y, false, false);
  x = (unsigned)r[0]; y = (unsigned)r[1];
}
// convert 8 f32 accumulator regs (C-layout rows) to one B-frag (proven R1/R2)
static __device__ __forceinline__ short8 conv8(const float* s, float iv){
  unsigned a0 = pk2bf(s[0]*iv, s[1]*iv);
  unsigned a1 = pk2bf(s[2]*iv, s[3]*iv);
  unsigned b0 = pk2bf(s[4]*iv, s[5]*iv);
  unsigned b1 = pk2bf(s[6]*iv, s[7]*iv);
  plswap(a0,b0); plswap(a1,b1);
  return mk8(a0,a1,b0,b1);
}

// ---------------------------------------------------------------------------
// Merged prep: [0,1024) wtrans ; [1024,2048) xhat (stats+normalize fused,
// one row per wave) ; [2048,2096) biasfold.
// ---------------------------------------------------------------------------
__global__ __launch_bounds__(256) void prep_kernel(
  const float* __restrict__ data,
  const float* __restrict__ Wq, const float* __restrict__ Wk,
  const float* __restrict__ Wv, const float* __restrict__ Wo,
  const float* __restrict__ gq, const float* __restrict__ gk, const float* __restrict__ gv,
  const float* __restrict__ blq, const float* __restrict__ blk, const float* __restrict__ blv,
  const float* __restrict__ bpq, const float* __restrict__ bpk, const float* __restrict__ bpv,
  unsigned short* __restrict__ WT, unsigned short* __restrict__ xhat,
  float* __restrict__ bf)
{
  __shared__ unsigned short tile[64][72];
  __shared__ float red[4][64];
  int bid = blockIdx.x, t = threadIdx.x;
  if (bid < 1024){
    // --- weight transpose + cast: WT[z][n][k] = scale_z[k] * W_z[k][n] ---
    int z = bid >> 8, rem = bid & 255;
    int k0 = (rem>>4)*64, n0 = (rem&15)*64;
    const float* W = (z==0)?Wq:(z==1)?Wk:(z==2)?Wv:Wo;
    const float* g = (z==0)?gq:(z==1)?gk:(z==2)?gv:(const float*)0;
    unsigned short* out = WT + ((size_t)z<<20);
    {
      int kr = t>>2, c16 = (t&3)*16;
      float gs = g ? g[k0+kr]*((z==0)?CE_:1.0f) : 1.0f;
      const float* src = W + (size_t)(k0+kr)*D_ + n0 + c16;
      float4 w0 = *(const float4*)(src);
      float4 w1 = *(const float4*)(src+4);
      float4 w2 = *(const float4*)(src+8);
      float4 w3 = *(const float4*)(src+12);
      unsigned* tp = (unsigned*)&tile[kr][c16];
      tp[0]=pk2bf(w0.x*gs,w0.y*gs); tp[1]=pk2bf(w0.z*gs,w0.w*gs);
      tp[2]=pk2bf(w1.x*gs,w1.y*gs); tp[3]=pk2bf(w1.z*gs,w1.w*gs);
      tp[4]=pk2bf(w2.x*gs,w2.y*gs); tp[5]=pk2bf(w2.z*gs,w2.w*gs);
      tp[6]=pk2bf(w3.x*gs,w3.y*gs); tp[7]=pk2bf(w3.z*gs,w3.w*gs);
    }
    __syncthreads();
    {
      int nr = t>>2, kc = (t&3)*16;
      union { uint4 v[2]; unsigned short u[16]; } st;
      #pragma unroll
      for (int i=0;i<16;i++) st.u[i] = tile[kc+i][nr];
      unsigned short* dst = out + (size_t)(n0+nr)*D_ + k0 + kc;
      *(uint4*)(dst)     = st.v[0];
      *(uint4*)(dst + 8) = st.v[1];
    }
  } else if (bid < 2048){
    // --- xhat: one row per wave, stats + normalize + bf16 store ---
    int row = (bid-1024)*4 + (t>>6);
    int l = t & 63;
    const float4* xr = (const float4*)(data + (size_t)row*D_);
    float4 v[4];
    float s = 0.f, ss = 0.f;
    #pragma unroll
    for (int i=0;i<4;i++){
      v[i] = xr[l + 64*i];
      s  += v[i].x+v[i].y+v[i].z+v[i].w;
      ss += v[i].x*v[i].x+v[i].y*v[i].y+v[i].z*v[i].z+v[i].w*v[i].w;
    }
    #pragma unroll
    for (int m=1;m<64;m<<=1){ s += __shfl_xor(s, m, 64); ss += __shfl_xor(ss, m, 64); }
    float me = s*(1.0f/D_);
    float var = ss*(1.0f/D_) - me*me;
    float rs = rsqrtf(var + 1e-5f);
    float nm = -me*rs;
    unsigned short* xo = xhat + (size_t)row*D_;
    #pragma unroll
    for (int i=0;i<4;i++){
      uint2 pk;
      pk.x = pk2bf(fmaf(v[i].x,rs,nm), fmaf(v[i].y,rs,nm));
      pk.y = pk2bf(fmaf(v[i].z,rs,nm), fmaf(v[i].w,rs,nm));
      *(uint2*)(xo + 4*l + 256*i) = pk;
    }
  } else {
    // --- folded bias ---
    int idx = bid - 2048;
    int z = idx >> 4, xb = idx & 15;
    const float* W  = (z==0)?Wq:(z==1)?Wk:Wv;
    const float* bl = (z==0)?blq:(z==1)?blk:blv;
    const float* bp = (z==0)?bpq:(z==1)?bpk:bpv;
    int nl = t & 63, kg = t >> 6;
    int n = xb*64 + nl;
    float acc = 0.f;
    for (int k = kg*256; k < (kg+1)*256; k++)
      acc += bl[k] * W[(size_t)k*D_ + n];
    red[kg][nl] = acc;
    __syncthreads();
    if (t < 64){
      int nn = xb*64 + t;
      float v = red[0][t]+red[1][t]+red[2][t]+red[3][t] + bp[nn];
      bf[z*D_ + nn] = (z==0) ? v*CE_ : v;
    }
  }
}

// ---------------------------------------------------------------------------
// Fused QKV GEMM, grid (32,8,3). 128x128 tile. Both tiles via glds width=16
// (A from precomputed bf16 xhat), unpadded stride-32 LDS.
// ---------------------------------------------------------------------------
__global__ __launch_bounds__(256) void gemm_qkv(
  const unsigned short* __restrict__ xhat,
  const unsigned short* __restrict__ WT,
  const float* __restrict__ biasf,
  unsigned short* __restrict__ qv, unsigned short* __restrict__ kb,
  unsigned short* __restrict__ kT, unsigned short* __restrict__ vT)
{
  int z = blockIdx.z;
  const unsigned short* Bt = WT + ((size_t)z<<20);
  const float* bias = biasf + z*D_;
  unsigned short* oN = (z==0)?qv:(z==1)?kb:(unsigned short*)0;
  unsigned short* oT = (z==0)?(unsigned short*)0:(z==1)?kT:vT;

  __shared__ __align__(16) unsigned short As[128*32];
  __shared__ __align__(16) unsigned short Bs[128*32];
  int tid = threadIdx.x, w = tid>>6, l = tid&63;
  int m0 = blockIdx.x*128, n0 = blockIdx.y*128;
  int wr = (w>>1)*64, wc = (w&1)*64;
  int lr = l&15, qd = l>>4;

  const unsigned short* gA = xhat + (size_t)(m0 + w*32 + (l>>2))*D_ + (l&3)*8;
  const unsigned short* gB = Bt   + (size_t)(n0 + w*32 + (l>>2))*D_ + (l&3)*8;
  unsigned short* lA0 = &As[(w*32)*32];
  unsigned short* lA1 = &As[(w*32+16)*32];
  unsigned short* lB0 = &Bs[(w*32)*32];
  unsigned short* lB1 = &Bs[(w*32+16)*32];

  const f32x4 fz = {0.f,0.f,0.f,0.f};
  f32x4 acc[4][4];
  #pragma unroll
  for (int i=0;i<4;i++)
    #pragma unroll
    for (int j=0;j<4;j++) acc[i][j] = fz;

  for (int kk=0; kk<D_; kk+=32){
    __syncthreads();
    glds16(gA + kk,                 lA0);
    glds16(gA + kk + (size_t)16*D_, lA1);
    glds16(gB + kk,                 lB0);
    glds16(gB + kk + (size_t)16*D_, lB1);
    __syncthreads();
    short8 af[4], bfr[4];
    #pragma unroll
    for (int i=0;i<4;i++) af[i]  = *(const short8*)(As + (wr + i*16 + lr)*32 + qd*8);
    #pragma unroll
    for (int j=0;j<4;j++) bfr[j] = *(const short8*)(Bs + (wc + j*16 + lr)*32 + qd*8);
    #pragma unroll
    for (int i=0;i<4;i++)
      #pragma unroll
      for (int j=0;j<4;j++)
        acc[i][j] = __builtin_amdgcn_mfma_f32_16x16x32_bf16(af[i], bfr[j], acc[i][j], 0, 0, 0);
  }

  #pragma unroll
  for (int j=0;j<4;j++){
    int n = n0 + wc + j*16 + lr;
    float bias_n = bias[n];
    #pragma unroll
    for (int i=0;i<4;i++){
      int mb = m0 + wr + i*16 + qd*4;
      float v0 = acc[i][j][0] + bias_n;
      float v1 = acc[i][j][1] + bias_n;
      float v2 = acc[i][j][2] + bias_n;
      float v3 = acc[i][j][3] + bias_n;
      if (oN){
        oN[(size_t)(mb+0)*D_ + n] = f2bfc(v0);
        oN[(size_t)(mb+1)*D_ + n] = f2bfc(v1);
        oN[(size_t)(mb+2)*D_ + n] = f2bfc(v2);
        oN[(size_t)(mb+3)*D_ + n] = f2bfc(v3);
      }
      if (oT){
        int bb = mb >> 11, sI = mb & (S_-1);
        int hh = n >> 6,  dd = n & 63;
        uint2 pk; pk.x = pk2bf(v0, v1); pk.y = pk2bf(v2, v3);
        *(uint2*)(oT + (size_t)((bb*H_ + hh)*HD_ + dd)*S_ + sI) = pk;
      }
    }
  }
}

// ---------------------------------------------------------------------------
// Out-projection: C = A(bf16) @ WTo^T + bo, f32 to d_out. Both tiles via glds.
// ---------------------------------------------------------------------------
__global__ __launch_bounds__(256) void gemm_out(
  const unsigned short* __restrict__ A,
  const unsigned short* __restrict__ Bt,
  const float* __restrict__ bo,
  float* __restrict__ Cf)
{
  __shared__ __align__(16) unsigned short As[128*32];
  __shared__ __align__(16) unsigned short Bs[128*32];
  int tid = threadIdx.x, w = tid>>6, l = tid&63;
  int m0 = blockIdx.x*128, n0 = blockIdx.y*128;
  int wr = (w>>1)*64, wc = (w&1)*64;
  int lr = l&15, qd = l>>4;

  const unsigned short* gA = A  + (size_t)(m0 + w*32 + (l>>2))*D_ + (l&3)*8;
  const unsigned short* gB = Bt + (size_t)(n0 + w*32 + (l>>2))*D_ + (l&3)*8;
  unsigned short* lA0 = &As[(w*32)*32];
  unsigned short* lA1 = &As[(w*32+16)*32];
  unsigned short* lB0 = &Bs[(w*32)*32];
  unsigned short* lB1 = &Bs[(w*32+16)*32];

  const f32x4 fz = {0.f,0.f,0.f,0.f};
  f32x4 acc[4][4];
  #pragma unroll
  for (int i=0;i<4;i++)
    #pragma unroll
    for (int j=0;j<4;j++) acc[i][j] = fz;

  for (int kk=0; kk<D_; kk+=32){
    __syncthreads();
    glds16(gA + kk,                 lA0);
    glds16(gA + kk + (size_t)16*D_, lA1);
    glds16(gB + kk,                 lB0);
    glds16(gB + kk + (size_t)16*D_, lB1);
    __syncthreads();
    short8 af[4], bfr[4];
    #pragma unroll
    for (int i=0;i<4;i++) af[i]  = *(const short8*)(As + (wr + i*16 + lr)*32 + qd*8);
    #pragma unroll
    for (int j=0;j<4;j++) bfr[j] = *(const short8*)(Bs + (wc + j*16 + lr)*32 + qd*8);
    #pragma unroll
    for (int i=0;i<4;i++)
      #pragma unroll
      for (int j=0;j<4;j++)
        acc[i][j] = __builtin_amdgcn_mfma_f32_16x16x32_bf16(af[i], bfr[j], acc[i][j], 0, 0, 0);
  }

  #pragma unroll
  for (int j=0;j<4;j++){
    int n = n0 + wc + j*16 + lr;
    float bias_n = bo[n];
    #pragma unroll
    for (int i=0;i<4;i++){
      int mb = m0 + wr + i*16 + qd*4;
      Cf[(size_t)(mb+0)*D_ + n] = acc[i][j][0] + bias_n;
      Cf[(size_t)(mb+1)*D_ + n] = acc[i][j][1] + bias_n;
      Cf[(size_t)(mb+2)*D_ + n] = acc[i][j][2] + bias_n;
      Cf[(size_t)(mb+3)*D_ + n] = acc[i][j][3] + bias_n;
    }
  }
}

// ---------------------------------------------------------------------------
// Fused double Hopfield attention. Grid (64,16), 256 threads.
// Wave w: kt-quarter (32 kt of the 128-kt superstep) x all 64 q-cols
// (2 col-tiles qc). Each LDS A-frag read feeds 2 MFMAs.
// Epilogue: combine 4 partial oacc/den across waves in 2 LDS chunks;
// wave w handles unit (dr=w>>1, rh=w&1) of each chunk.
// ---------------------------------------------------------------------------
__global__ __launch_bounds__(256, 4) void attn_fused(
  unsigned short* __restrict__ QO,
  const unsigned short* __restrict__ K,
  const unsigned short* __restrict__ KT,
  const unsigned short* __restrict__ VT)
{
  int qt = blockIdx.x;           // 0..63 -> 64 q-rows
  int h  = blockIdx.y;           // 0..15
  int b  = qt >> 5;
  int bh = b*H_ + h;
  int tid = threadIdx.x, w = tid>>6, l = tid&63;
  int lq = l & 31, hi = l >> 5;
  int swzr = (lq & 7) << 3;
  int dr_ = w >> 1, rh_ = w & 1;   // epilogue unit owned by this wave

  __shared__ __align__(16) unsigned short smem[17408];  // 34 KB
  unsigned short* sK = smem;           // [128][64] shorts
  unsigned short* sV = smem + 8192;    // [64][128] shorts
  float* dn = (float*)(smem + 16384);  // 512 floats (den partials)

  const f32x16 fz16 = {0.f,0.f,0.f,0.f,0.f,0.f,0.f,0.f,
                       0.f,0.f,0.f,0.f,0.f,0.f,0.f,0.f};
  const f32x2 fz2 = {0.f,0.f};

  // ---- initial Q fragments: qf[qc][d4], B-frag k = hi*8+i, col = lq ----
  const unsigned short* Qb = QO + (size_t)(qt*64 + lq)*D_ + h*64;
  short8 qf[2][4];
  #pragma unroll
  for (int qc=0; qc<2; qc++)
    #pragma unroll
    for (int d=0; d<4; d++)
      qf[qc][d] = *(const short8*)(Qb + (size_t)qc*32*D_ + d*16 + hi*8);

  const unsigned short* Khead = K + (size_t)(b*S_)*D_ + h*64;
  const unsigned short* Vh0 = KT + (size_t)bh*HD_*S_;
  const unsigned short* Vh1 = VT + (size_t)bh*HD_*S_;

  // ---- staging geometry (pre-swizzled global sources, linear LDS) ----
  int seg = w*4;
  int kcol = ((l&7)*8) ^ (((l>>3)&7)*8);
  const unsigned short* gKb = Khead + (size_t)(seg*8 + (l>>3))*D_ + kcol;
  int vrE = seg*4 + (l>>4);                      // rows for j=0 (j=2: +8)
  int vcE = ((l&15)*8) ^ (((l>>4)&7)*8);
  int vcO = ((l&15)*8) ^ ((((l>>4)+4)&7)*8);     // j odd: row&7 = 4+(l>>4)

  unsigned short* lK0 = sK + (seg+0)*512;
  unsigned short* lK1 = sK + (seg+1)*512;
  unsigned short* lK2 = sK + (seg+2)*512;
  unsigned short* lK3 = sK + (seg+3)*512;
  unsigned short* lV0 = sV + (seg+0)*512;
  unsigned short* lV1 = sV + (seg+1)*512;
  unsigned short* lV2 = sV + (seg+2)*512;
  unsigned short* lV3 = sV + (seg+3)*512;

  #pragma unroll 1
  for (int phase=0; phase<2; phase++){
    const unsigned short* Vhead = phase ? Vh1 : Vh0;
    const unsigned short* gK  = gKb;
    const unsigned short* gV0 = Vhead + (size_t)(vrE  )*S_ + vcE;
    const unsigned short* gV1 = Vhead + (size_t)(vrE+4)*S_ + vcO;

    f32x16 oacc[2][2];
    oacc[0][0]=fz16; oacc[0][1]=fz16; oacc[1][0]=fz16; oacc[1][1]=fz16;
    f32x2 dq0 = fz2, dq1 = fz2;

    #pragma unroll 1
    for (int ss=0; ss<16; ss++){
      __syncthreads();                 // prior readers done with smem
      glds16(gK,          lK0);
      glds16(gK +  8*D_,  lK1);
      glds16(gK + 16*D_,  lK2);
      glds16(gK + 24*D_,  lK3);
      glds16(gV0,         lV0);
      glds16(gV1,         lV1);
      glds16(gV0 + 8*S_,  lV2);
      glds16(gV1 + 8*S_,  lV3);
      __syncthreads();                 // drains vmcnt -> tiles visible
      gK  += 128*D_;
      gV0 += 128;
      gV1 += 128;

      // --- QK^T on this wave's 32-kt quarter: S^T[kt][q], 2 q-tiles ---
      f32x16 sc0 = fz16, sc1 = fz16;
      __builtin_amdgcn_s_setprio(1);
      #pragma unroll
      for (int d4=0; d4<4; d4++){
        short8 ka = *(const short8*)(&sK[(size_t)(w*32 + lq)*64 + ((d4*16 + hi*8) ^ swzr)]);
        sc0 = __builtin_amdgcn_mfma_f32_32x32x16_bf16(ka, qf[0][d4], sc0, 0,0,0);
        sc1 = __builtin_amdgcn_mfma_f32_32x32x16_bf16(ka, qf[1][d4], sc1, 0,0,0);
      }
      __builtin_amdgcn_s_setprio(0);

      // --- exp2 (in place), packed den accumulation ---
      #pragma unroll
      for (int i=0;i<16;i++){
        sc0[i] = __builtin_amdgcn_exp2f(sc0[i]);
        sc1[i] = __builtin_amdgcn_exp2f(sc1[i]);
      }
      #pragma unroll
      for (int i=0;i<16;i+=2){
        dq0 += (f32x2){sc0[i], sc0[i+1]};
        dq1 += (f32x2){sc1[i], sc1[i+1]};
      }

      // --- in-register P -> B-frag conversion (T12) ---
      short8 pf0[2], pf1[2];
      {
        unsigned a0,a1,b0,b1;
        a0=pk2bft(sc0[0],sc0[1]);   a1=pk2bft(sc0[2],sc0[3]);
        b0=pk2bft(sc0[4],sc0[5]);   b1=pk2bft(sc0[6],sc0[7]);
        plswap(a0,b0); plswap(a1,b1);
        pf0[0] = mk8(a0,a1,b0,b1);
        a0=pk2bft(sc0[8],sc0[9]);   a1=pk2bft(sc0[10],sc0[11]);
        b0=pk2bft(sc0[12],sc0[13]); b1=pk2bft(sc0[14],sc0[15]);
        plswap(a0,b0); plswap(a1,b1);
        pf0[1] = mk8(a0,a1,b0,b1);
        a0=pk2bft(sc1[0],sc1[1]);   a1=pk2bft(sc1[2],sc1[3]);
        b0=pk2bft(sc1[4],sc1[5]);   b1=pk2bft(sc1[6],sc1[7]);
        plswap(a0,b0); plswap(a1,b1);
        pf1[0] = mk8(a0,a1,b0,b1);
        a0=pk2bft(sc1[8],sc1[9]);   a1=pk2bft(sc1[10],sc1[11]);
        b0=pk2bft(sc1[12],sc1[13]); b1=pk2bft(sc1[14],sc1[15]);
        plswap(a0,b0); plswap(a1,b1);
        pf1[1] = mk8(a0,a1,b0,b1);
      }

      // --- PV: O^T[d][q] += V^T-tile x P (kt = this wave's quarter) ---
      __builtin_amdgcn_s_setprio(1);
      #pragma unroll
      for (int dr=0; dr<2; dr++){
        #pragma unroll
        for (int ks=0; ks<2; ks++){
          short8 va = *(const short8*)(&sV[(size_t)(dr*32 + lq)*128 + ((w*32 + ks*16 + hi*8) ^ swzr)]);
          oacc[0][dr] = __builtin_amdgcn_mfma_f32_32x32x16_bf16(va, pf0[ks], oacc[0][dr], 0,0,0);
          oacc[1][dr] = __builtin_amdgcn_mfma_f32_32x32x16_bf16(va, pf1[ks], oacc[1][dr], 0,0,0);
        }
      }
      __builtin_amdgcn_s_setprio(0);
    } // ss

    // ---- epilogue: combine 4 wave-partials (2 chunks of 32KB) ----
    float den0 = dq0.x + dq0.y; den0 += __shfl_xor(den0, 32, 64);
    float den1 = dq1.x + dq1.y; den1 += __shfl_xor(den1, 32, 64);

    float* fb = (float*)smem;
    __syncthreads();                   // everyone done with sK/sV
    // chunk 0: oacc[qc=0] + den partials
    #pragma unroll
    for (int dr=0; dr<2; dr++)
      #pragma unroll
      for (int g=0; g<16; g++)
        fb[w*2048 + (dr*16+g)*64 + l] = oacc[0][dr][g];
    dn[w*64 + l]       = den0;
    dn[256 + w*64 + l] = den1;
    __syncthreads();
    float s0[8], dt0, dt1;
    {
      #pragma unroll
      for (int j=0;j<8;j++){
        int off = (dr_*16 + rh_*8 + j)*64 + l;
        s0[j] = (fb[off] + fb[2048+off]) + (fb[4096+off] + fb[6144+off]);
      }
      dt0 = (dn[l] + dn[64+l]) + (dn[128+l] + dn[192+l]);
      dt1 = (dn[256+l] + dn[320+l]) + (dn[384+l] + dn[448+l]);
    }
    __syncthreads();                   // chunk-0 reads done
    // chunk 1: oacc[qc=1]
    #pragma unroll
    for (int dr=0; dr<2; dr++)
      #pragma unroll
      for (int g=0; g<16; g++)
        fb[w*2048 + (dr*16+g)*64 + l] = oacc[1][dr][g];
    __syncthreads();
    float s1[8];
    #pragma unroll
    for (int j=0;j<8;j++){
      int off = (dr_*16 + rh_*8 + j)*64 + l;
      s1[j] = (fb[off] + fb[2048+off]) + (fb[4096+off] + fb[6144+off]);
    }

    if (phase==0){
      // q <- (xi K) * CE, as B-frags; this wave produces 2 of the 8 frags
      short8 f0 = conv8(s0, CE_ * __builtin_amdgcn_rcpf(dt0));
      short8 f1 = conv8(s1, CE_ * __builtin_amdgcn_rcpf(dt1));
      __syncthreads();                 // chunk-1 reads done
      *(short8*)(smem + (size_t)(0*4 + w)*512 + l*8) = f0;
      *(short8*)(smem + (size_t)(1*4 + w)*512 + l*8) = f1;
      __syncthreads();
      #pragma unroll
      for (int qc=0; qc<2; qc++)
        #pragma unroll
        for (int ds=0; ds<4; ds++)
          qf[qc][ds] = *(const short8*)(smem + (size_t)(qc*4 + ds)*512 + l*8);
    } else {
      // final store: this wave stores its (dr_, rh_) unit for both qc
      float iv0 = __builtin_amdgcn_rcpf(dt0);
      float iv1 = __builtin_amdgcn_rcpf(dt1);
      unsigned short* Ob0 = QO + (size_t)(qt*64 + 0*32 + lq)*D_ + h*64 + dr_*32 + hi*4;
      unsigned short* Ob1 = QO + (size_t)(qt*64 + 1*32 + lq)*D_ + h*64 + dr_*32 + hi*4;
      #pragma unroll
      for (int gg=0; gg<2; gg++){
        uint2 pk;
        pk.x = pk2bf(s0[gg*4+0]*iv0, s0[gg*4+1]*iv0);
        pk.y = pk2bf(s0[gg*4+2]*iv0, s0[gg*4+3]*iv0);
        *(uint2*)(Ob0 + (rh_*2+gg)*8) = pk;
        pk.x = pk2bf(s1[gg*4+0]*iv1, s1[gg*4+1]*iv1);
        pk.y = pk2bf(s1[gg*4+2]*iv1, s1[gg*4+3]*iv1);
        *(uint2*)(Ob1 + (rh_*2+gg)*8) = pk;
      }
    }
  } // phase
}

// ---------------------------------------------------------------------------
extern "C" void kernel_launch(void* const* d_in, const int* in_sizes, int n_in,
                              void* d_out, int out_size, void* d_ws, size_t ws_size,
                              hipStream_t stream){
  const float* data = (const float*)d_in[0];
  const float* g_k  = (const float*)d_in[1];
  const float* b_k  = (const float*)d_in[2];
  const float* g_q  = (const float*)d_in[3];
  const float* b_q  = (const float*)d_in[4];
  const float* g_v  = (const float*)d_in[5];
  const float* b_v  = (const float*)d_in[6];
  const float* Wq   = (const float*)d_in[7];
  const float* bq   = (const float*)d_in[8];
  const float* Wk   = (const float*)d_in[9];
  const float* bk   = (const float*)d_in[10];
  const float* Wv   = (const float*)d_in[11];
  const float* bv   = (const float*)d_in[12];
  const float* Wo   = (const float*)d_in[13];
  const float* bo   = (const float*)d_in[14];
  float* out = (float*)d_out;

  char* ws = (char*)d_ws;
  const size_t MB = (size_t)1<<20;
  unsigned short* q    = (unsigned short*)(ws);
  unsigned short* kb   = (unsigned short*)(ws + 8*MB);
  unsigned short* WT   = (unsigned short*)(ws + 16*MB);
  unsigned short* WTo  = WT + ((size_t)3<<20);
  unsigned short* xhat = (unsigned short*)(ws + 24*MB);
  float*          bfld = (float*)(ws + 32*MB);
  unsigned short* vT   = (unsigned short*)d_out;
  unsigned short* kT   = (unsigned short*)((char*)d_out + 8*MB);

  dim3 gb(256);
  prep_kernel<<<dim3(2096), gb, 0, stream>>>(data,
                                             Wq, Wk, Wv, Wo, g_q, g_k, g_v,
                                             b_q, b_k, b_v, bq, bk, bv,
                                             WT, xhat, bfld);
  gemm_qkv<<<dim3(32,8,3), gb, 0, stream>>>(xhat, WT, bfld, q, kb, kT, vT);
  attn_fused<<<dim3(64, H_), gb, 0, stream>>>(q, kb, kT, vT);
  gemm_out<<<dim3(32,8), gb, 0, stream>>>(q, WTo, bo, out);
}

// Round 4
// 254.569 us; speedup vs baseline: 1.5208x; 1.5208x over previous
//
#include <hip/hip_runtime.h>
#include <hip/hip_bf16.h>

// Problem constants
#define B_  2
#define S_  2048
#define D_  1024
#define H_  16
#define HD_ 64
#define M_  4096   // B_*S_

// Inputs/outputs f32; internal compute bf16 MFMA with f32 accumulation.
// ws (32 MB + 12 KB):
//   [0,8)MB  q bf16 (CE-prescaled via WTq/biasf; attn in-place)
//   [8,16)MB kb bf16
//   [16,24)MB WT bf16: 4 x [1024][1024] ([q CE*g | k g | v g | o plain])
//   [24,32)MB xhat bf16 [4096][1024]  (LN(data), affine folded into WT/biasf)
//   +32MB: biasf f32[3][1024]
// d_out (16 MB f32) as scratch until the final GEMM:
//   [0,8)MB vT bf16 [bh][d][s]   [8,16)MB kT bf16 [bh][d][s]
//
// attn_fused (this round): R2 structure (wq x wk wave split, proven
// 96us) + async double-buffered staging. Superstep = 64 kt (16KB),
// two buffers (32KB) + den (2KB) = 34KB. Per ss: issue next tile's
// 4 glds (sched_barrier-pinned early), compute current buffer, ONE
// barrier (drains vmcnt after compute -> stage latency hidden).
// R3's register-doubling reverted (spill storm: WRITE_SIZE 14->213MB).

typedef __attribute__((ext_vector_type(8))) short short8;
typedef __attribute__((ext_vector_type(4))) float f32x4;
typedef __attribute__((ext_vector_type(2))) float f32x2;
typedef __attribute__((ext_vector_type(16))) float f32x16;

#define CE_ 0.1803368801111204f   // 0.125 * log2(e)

typedef __attribute__((address_space(1))) const unsigned GU;
typedef __attribute__((address_space(3))) unsigned LU;
static __device__ __forceinline__ void glds16(const void* g, void* l){
  __builtin_amdgcn_global_load_lds((GU*)g, (LU*)l, 16, 0, 0);
}

static __device__ __forceinline__ unsigned short f2bfc(float f){
  union{float f; unsigned u;} c; c.f = f;
  return (unsigned short)((c.u + 0x8000u) >> 16);
}
static __device__ __forceinline__ unsigned pk2bf(float a, float b){
  union{float f; unsigned u;} ca, cb; ca.f=a; cb.f=b;
  return __builtin_amdgcn_perm(cb.u + 0x8000u, ca.u + 0x8000u, 0x07060302u);
}
static __device__ __forceinline__ unsigned pk2bft(float a, float b){
  union{float f; unsigned u;} ca, cb; ca.f=a; cb.f=b;
  return __builtin_amdgcn_perm(cb.u, ca.u, 0x07060302u);
}
static __device__ __forceinline__ short8 mk8(unsigned x0, unsigned x1,
                                             unsigned x2, unsigned x3){
  union{ unsigned u[4]; short8 s; } t;
  t.u[0]=x0; t.u[1]=x1; t.u[2]=x2; t.u[3]=x3; return t.s;
}
// v_permlane32_swap_b32: new_x[32:63] = old_y[0:31]; new_y[0:31] = old_x[32:63]
static __device__ __forceinline__ void plswap(unsigned &x, unsigned &y){
  auto r = __builtin_amdgcn_permlane32_swap(x, y, false, false);
  x = (unsigned)r[0]; y = (unsigned)r[1];
}
// convert C-layout f32 rows -> one B-frag (proven R1/R2). a: regs 0..7 / 8..15
static __device__ __forceinline__ short8 conv8a(const f32x16& v, float iv){
  unsigned a0 = pk2bf(v[0]*iv, v[1]*iv);
  unsigned a1 = pk2bf(v[2]*iv, v[3]*iv);
  unsigned b0 = pk2bf(v[4]*iv, v[5]*iv);
  unsigned b1 = pk2bf(v[6]*iv, v[7]*iv);
  plswap(a0,b0); plswap(a1,b1);
  return mk8(a0,a1,b0,b1);
}
static __device__ __forceinline__ short8 conv8b(const f32x16& v, float iv){
  unsigned a0 = pk2bf(v[8]*iv,  v[9]*iv);
  unsigned a1 = pk2bf(v[10]*iv, v[11]*iv);
  unsigned b0 = pk2bf(v[12]*iv, v[13]*iv);
  unsigned b1 = pk2bf(v[14]*iv, v[15]*iv);
  plswap(a0,b0); plswap(a1,b1);
  return mk8(a0,a1,b0,b1);
}

// ---------------------------------------------------------------------------
// Merged prep: [0,1024) wtrans ; [1024,2048) xhat (stats+normalize fused,
// one row per wave) ; [2048,2096) biasfold.
// ---------------------------------------------------------------------------
__global__ __launch_bounds__(256) void prep_kernel(
  const float* __restrict__ data,
  const float* __restrict__ Wq, const float* __restrict__ Wk,
  const float* __restrict__ Wv, const float* __restrict__ Wo,
  const float* __restrict__ gq, const float* __restrict__ gk, const float* __restrict__ gv,
  const float* __restrict__ blq, const float* __restrict__ blk, const float* __restrict__ blv,
  const float* __restrict__ bpq, const float* __restrict__ bpk, const float* __restrict__ bpv,
  unsigned short* __restrict__ WT, unsigned short* __restrict__ xhat,
  float* __restrict__ bf)
{
  __shared__ unsigned short tile[64][72];
  __shared__ float red[4][64];
  int bid = blockIdx.x, t = threadIdx.x;
  if (bid < 1024){
    // --- weight transpose + cast: WT[z][n][k] = scale_z[k] * W_z[k][n] ---
    int z = bid >> 8, rem = bid & 255;
    int k0 = (rem>>4)*64, n0 = (rem&15)*64;
    const float* W = (z==0)?Wq:(z==1)?Wk:(z==2)?Wv:Wo;
    const float* g = (z==0)?gq:(z==1)?gk:(z==2)?gv:(const float*)0;
    unsigned short* out = WT + ((size_t)z<<20);
    {
      int kr = t>>2, c16 = (t&3)*16;
      float gs = g ? g[k0+kr]*((z==0)?CE_:1.0f) : 1.0f;
      const float* src = W + (size_t)(k0+kr)*D_ + n0 + c16;
      float4 w0 = *(const float4*)(src);
      float4 w1 = *(const float4*)(src+4);
      float4 w2 = *(const float4*)(src+8);
      float4 w3 = *(const float4*)(src+12);
      unsigned* tp = (unsigned*)&tile[kr][c16];
      tp[0]=pk2bf(w0.x*gs,w0.y*gs); tp[1]=pk2bf(w0.z*gs,w0.w*gs);
      tp[2]=pk2bf(w1.x*gs,w1.y*gs); tp[3]=pk2bf(w1.z*gs,w1.w*gs);
      tp[4]=pk2bf(w2.x*gs,w2.y*gs); tp[5]=pk2bf(w2.z*gs,w2.w*gs);
      tp[6]=pk2bf(w3.x*gs,w3.y*gs); tp[7]=pk2bf(w3.z*gs,w3.w*gs);
    }
    __syncthreads();
    {
      int nr = t>>2, kc = (t&3)*16;
      union { uint4 v[2]; unsigned short u[16]; } st;
      #pragma unroll
      for (int i=0;i<16;i++) st.u[i] = tile[kc+i][nr];
      unsigned short* dst = out + (size_t)(n0+nr)*D_ + k0 + kc;
      *(uint4*)(dst)     = st.v[0];
      *(uint4*)(dst + 8) = st.v[1];
    }
  } else if (bid < 2048){
    // --- xhat: one row per wave, stats + normalize + bf16 store ---
    int row = (bid-1024)*4 + (t>>6);
    int l = t & 63;
    const float4* xr = (const float4*)(data + (size_t)row*D_);
    float4 v[4];
    float s = 0.f, ss = 0.f;
    #pragma unroll
    for (int i=0;i<4;i++){
      v[i] = xr[l + 64*i];
      s  += v[i].x+v[i].y+v[i].z+v[i].w;
      ss += v[i].x*v[i].x+v[i].y*v[i].y+v[i].z*v[i].z+v[i].w*v[i].w;
    }
    #pragma unroll
    for (int m=1;m<64;m<<=1){ s += __shfl_xor(s, m, 64); ss += __shfl_xor(ss, m, 64); }
    float me = s*(1.0f/D_);
    float var = ss*(1.0f/D_) - me*me;
    float rs = rsqrtf(var + 1e-5f);
    float nm = -me*rs;
    unsigned short* xo = xhat + (size_t)row*D_;
    #pragma unroll
    for (int i=0;i<4;i++){
      uint2 pk;
      pk.x = pk2bf(fmaf(v[i].x,rs,nm), fmaf(v[i].y,rs,nm));
      pk.y = pk2bf(fmaf(v[i].z,rs,nm), fmaf(v[i].w,rs,nm));
      *(uint2*)(xo + 4*l + 256*i) = pk;
    }
  } else {
    // --- folded bias ---
    int idx = bid - 2048;
    int z = idx >> 4, xb = idx & 15;
    const float* W  = (z==0)?Wq:(z==1)?Wk:Wv;
    const float* bl = (z==0)?blq:(z==1)?blk:blv;
    const float* bp = (z==0)?bpq:(z==1)?bpk:bpv;
    int nl = t & 63, kg = t >> 6;
    int n = xb*64 + nl;
    float acc = 0.f;
    for (int k = kg*256; k < (kg+1)*256; k++)
      acc += bl[k] * W[(size_t)k*D_ + n];
    red[kg][nl] = acc;
    __syncthreads();
    if (t < 64){
      int nn = xb*64 + t;
      float v = red[0][t]+red[1][t]+red[2][t]+red[3][t] + bp[nn];
      bf[z*D_ + nn] = (z==0) ? v*CE_ : v;
    }
  }
}

// ---------------------------------------------------------------------------
// Fused QKV GEMM, grid (32,8,3). 128x128 tile. Both tiles via glds width=16
// (A from precomputed bf16 xhat), unpadded stride-32 LDS.
// ---------------------------------------------------------------------------
__global__ __launch_bounds__(256) void gemm_qkv(
  const unsigned short* __restrict__ xhat,
  const unsigned short* __restrict__ WT,
  const float* __restrict__ biasf,
  unsigned short* __restrict__ qv, unsigned short* __restrict__ kb,
  unsigned short* __restrict__ kT, unsigned short* __restrict__ vT)
{
  int z = blockIdx.z;
  const unsigned short* Bt = WT + ((size_t)z<<20);
  const float* bias = biasf + z*D_;
  unsigned short* oN = (z==0)?qv:(z==1)?kb:(unsigned short*)0;
  unsigned short* oT = (z==0)?(unsigned short*)0:(z==1)?kT:vT;

  __shared__ __align__(16) unsigned short As[128*32];
  __shared__ __align__(16) unsigned short Bs[128*32];
  int tid = threadIdx.x, w = tid>>6, l = tid&63;
  int m0 = blockIdx.x*128, n0 = blockIdx.y*128;
  int wr = (w>>1)*64, wc = (w&1)*64;
  int lr = l&15, qd = l>>4;

  const unsigned short* gA = xhat + (size_t)(m0 + w*32 + (l>>2))*D_ + (l&3)*8;
  const unsigned short* gB = Bt   + (size_t)(n0 + w*32 + (l>>2))*D_ + (l&3)*8;
  unsigned short* lA0 = &As[(w*32)*32];
  unsigned short* lA1 = &As[(w*32+16)*32];
  unsigned short* lB0 = &Bs[(w*32)*32];
  unsigned short* lB1 = &Bs[(w*32+16)*32];

  const f32x4 fz = {0.f,0.f,0.f,0.f};
  f32x4 acc[4][4];
  #pragma unroll
  for (int i=0;i<4;i++)
    #pragma unroll
    for (int j=0;j<4;j++) acc[i][j] = fz;

  for (int kk=0; kk<D_; kk+=32){
    __syncthreads();
    glds16(gA + kk,                 lA0);
    glds16(gA + kk + (size_t)16*D_, lA1);
    glds16(gB + kk,                 lB0);
    glds16(gB + kk + (size_t)16*D_, lB1);
    __syncthreads();
    short8 af[4], bfr[4];
    #pragma unroll
    for (int i=0;i<4;i++) af[i]  = *(const short8*)(As + (wr + i*16 + lr)*32 + qd*8);
    #pragma unroll
    for (int j=0;j<4;j++) bfr[j] = *(const short8*)(Bs + (wc + j*16 + lr)*32 + qd*8);
    #pragma unroll
    for (int i=0;i<4;i++)
      #pragma unroll
      for (int j=0;j<4;j++)
        acc[i][j] = __builtin_amdgcn_mfma_f32_16x16x32_bf16(af[i], bfr[j], acc[i][j], 0, 0, 0);
  }

  #pragma unroll
  for (int j=0;j<4;j++){
    int n = n0 + wc + j*16 + lr;
    float bias_n = bias[n];
    #pragma unroll
    for (int i=0;i<4;i++){
      int mb = m0 + wr + i*16 + qd*4;
      float v0 = acc[i][j][0] + bias_n;
      float v1 = acc[i][j][1] + bias_n;
      float v2 = acc[i][j][2] + bias_n;
      float v3 = acc[i][j][3] + bias_n;
      if (oN){
        oN[(size_t)(mb+0)*D_ + n] = f2bfc(v0);
        oN[(size_t)(mb+1)*D_ + n] = f2bfc(v1);
        oN[(size_t)(mb+2)*D_ + n] = f2bfc(v2);
        oN[(size_t)(mb+3)*D_ + n] = f2bfc(v3);
      }
      if (oT){
        int bb = mb >> 11, sI = mb & (S_-1);
        int hh = n >> 6,  dd = n & 63;
        uint2 pk; pk.x = pk2bf(v0, v1); pk.y = pk2bf(v2, v3);
        *(uint2*)(oT + (size_t)((bb*H_ + hh)*HD_ + dd)*S_ + sI) = pk;
      }
    }
  }
}

// ---------------------------------------------------------------------------
// Out-projection: C = A(bf16) @ WTo^T + bo, f32 to d_out. Both tiles via glds.
// ---------------------------------------------------------------------------
__global__ __launch_bounds__(256) void gemm_out(
  const unsigned short* __restrict__ A,
  const unsigned short* __restrict__ Bt,
  const float* __restrict__ bo,
  float* __restrict__ Cf)
{
  __shared__ __align__(16) unsigned short As[128*32];
  __shared__ __align__(16) unsigned short Bs[128*32];
  int tid = threadIdx.x, w = tid>>6, l = tid&63;
  int m0 = blockIdx.x*128, n0 = blockIdx.y*128;
  int wr = (w>>1)*64, wc = (w&1)*64;
  int lr = l&15, qd = l>>4;

  const unsigned short* gA = A  + (size_t)(m0 + w*32 + (l>>2))*D_ + (l&3)*8;
  const unsigned short* gB = Bt + (size_t)(n0 + w*32 + (l>>2))*D_ + (l&3)*8;
  unsigned short* lA0 = &As[(w*32)*32];
  unsigned short* lA1 = &As[(w*32+16)*32];
  unsigned short* lB0 = &Bs[(w*32)*32];
  unsigned short* lB1 = &Bs[(w*32+16)*32];

  const f32x4 fz = {0.f,0.f,0.f,0.f};
  f32x4 acc[4][4];
  #pragma unroll
  for (int i=0;i<4;i++)
    #pragma unroll
    for (int j=0;j<4;j++) acc[i][j] = fz;

  for (int kk=0; kk<D_; kk+=32){
    __syncthreads();
    glds16(gA + kk,                 lA0);
    glds16(gA + kk + (size_t)16*D_, lA1);
    glds16(gB + kk,                 lB0);
    glds16(gB + kk + (size_t)16*D_, lB1);
    __syncthreads();
    short8 af[4], bfr[4];
    #pragma unroll
    for (int i=0;i<4;i++) af[i]  = *(const short8*)(As + (wr + i*16 + lr)*32 + qd*8);
    #pragma unroll
    for (int j=0;j<4;j++) bfr[j] = *(const short8*)(Bs + (wc + j*16 + lr)*32 + qd*8);
    #pragma unroll
    for (int i=0;i<4;i++)
      #pragma unroll
      for (int j=0;j<4;j++)
        acc[i][j] = __builtin_amdgcn_mfma_f32_16x16x32_bf16(af[i], bfr[j], acc[i][j], 0, 0, 0);
  }

  #pragma unroll
  for (int j=0;j<4;j++){
    int n = n0 + wc + j*16 + lr;
    float bias_n = bo[n];
    #pragma unroll
    for (int i=0;i<4;i++){
      int mb = m0 + wr + i*16 + qd*4;
      Cf[(size_t)(mb+0)*D_ + n] = acc[i][j][0] + bias_n;
      Cf[(size_t)(mb+1)*D_ + n] = acc[i][j][1] + bias_n;
      Cf[(size_t)(mb+2)*D_ + n] = acc[i][j][2] + bias_n;
      Cf[(size_t)(mb+3)*D_ + n] = acc[i][j][3] + bias_n;
    }
  }
}

// ---------------------------------------------------------------------------
// Fused double Hopfield attention, async double-buffered. Grid (64,16),
// 256 threads. Wave (wq=w&1, wk=w>>1): wq = 32-row q-subtile, wk = 32-kt
// half of the 64-kt superstep. Buffers: buf b at smem + b*8192 shorts
// ([sK 64x64][sV 64x64]); den at +16384; epilogue scratch = buf1 region.
// Per ss: stage(t+1) -> sched_barrier -> compute(buf t&1) -> 1 barrier.
// ---------------------------------------------------------------------------
__global__ __launch_bounds__(256, 4) void attn_fused(
  unsigned short* __restrict__ QO,
  const unsigned short* __restrict__ K,
  const unsigned short* __restrict__ KT,
  const unsigned short* __restrict__ VT)
{
  int qt = blockIdx.x;           // 0..63 -> 64 q-rows
  int h  = blockIdx.y;           // 0..15
  int b  = qt >> 5;
  int bh = b*H_ + h;
  int tid = threadIdx.x, w = tid>>6, l = tid&63;
  int wq = w & 1, wk = w >> 1;
  int lq = l & 31, hi = l >> 5;
  int swzr = (lq & 7) << 3;

  __shared__ __align__(16) unsigned short smem[17408];  // 34 KB

  const f32x16 fz16 = {0.f,0.f,0.f,0.f,0.f,0.f,0.f,0.f,
                       0.f,0.f,0.f,0.f,0.f,0.f,0.f,0.f};

  // ---- initial Q fragments (B-frag: k = hi*8+i, col = lq) ----
  const unsigned short* Qb = QO + (size_t)(qt*64 + wq*32 + lq)*D_ + h*64;
  short8 qf[4];
  #pragma unroll
  for (int d=0; d<4; d++) qf[d] = *(const short8*)(Qb + d*16 + hi*8);

  const unsigned short* Khead = K + (size_t)(b*S_)*D_ + h*64;
  const unsigned short* Vh0 = KT + (size_t)bh*HD_*S_;
  const unsigned short* Vh1 = VT + (size_t)bh*HD_*S_;

  // ---- staging geometry (pre-swizzled global sources, linear LDS) ----
  // wave w stages K rows [seg0*8, seg0*8+16) and V rows [seg0*8, +16)
  int seg0 = w*2;
  int lr8 = l>>3;
  int swzs = ((l&7)*8) ^ (lr8*8);
  const unsigned short* gKs  = Khead + (size_t)(seg0*8 + lr8)*D_ + swzs;
  const unsigned short* gV0s = Vh0 + (size_t)(seg0*8 + lr8)*S_ + swzs;
  const unsigned short* gV1s = Vh1 + (size_t)(seg0*8 + lr8)*S_ + swzs;
  int dK0 = seg0*512 + l*8;          // shorts, + buf*8192
  int dV0 = 4096 + seg0*512 + l*8;

  // ---- prologue: stage t=0 into buf0 ----
  glds16(gKs,         smem + dK0);
  glds16(gKs + 8*D_,  smem + dK0 + 512);
  glds16(gV0s,        smem + dV0);
  glds16(gV0s + 8*S_, smem + dV0 + 512);
  __syncthreads();

  #pragma unroll 1
  for (int phase=0; phase<2; phase++){
    f32x16 oacc[2]; oacc[0]=fz16; oacc[1]=fz16;
    f32x2 dq = {0.f,0.f};

    #pragma unroll 1
    for (int ss=0; ss<32; ss++){
      int t = phase*32 + ss;
      // --- stage t+1 into buf (t+1)&1 (skipped on the very last step) ---
      if (t < 63){
        int tn = t + 1;
        int tt = tn & 31;
        unsigned short* bb = smem + ((tn&1) ? 8192 : 0);
        const unsigned short* gk = gKs + (size_t)tt*64*D_;
        const unsigned short* gv = ((tn >= 32) ? gV1s : gV0s) + tt*64;
        glds16(gk,         bb + dK0);
        glds16(gk + 8*D_,  bb + dK0 + 512);
        glds16(gv,         bb + dV0);
        glds16(gv + 8*S_,  bb + dV0 + 512);
      }
      __builtin_amdgcn_sched_barrier(0);   // keep stage issue before compute

      const unsigned short* sKc = smem + ((t&1) ? 8192 : 0);
      const unsigned short* sVc = sKc + 4096;

      // --- QK^T on this wave's 32-kt half: S^T[kt][q] ---
      f32x16 sc = fz16;
      __builtin_amdgcn_s_setprio(1);
      #pragma unroll
      for (int d4=0; d4<4; d4++){
        short8 ka = *(const short8*)(sKc + (size_t)(wk*32 + lq)*64 + ((d4*16 + hi*8) ^ swzr));
        sc = __builtin_amdgcn_mfma_f32_32x32x16_bf16(ka, qf[d4], sc, 0,0,0);
      }
      __builtin_amdgcn_s_setprio(0);

      // --- exp2 + packed den accumulation ---
      #pragma unroll
      for (int i=0;i<16;i++) sc[i] = __builtin_amdgcn_exp2f(sc[i]);
      #pragma unroll
      for (int i=0;i<16;i+=2) dq += (f32x2){sc[i], sc[i+1]};

      // --- in-register P -> B-frag conversion (T12) ---
      short8 pf[2];
      {
        unsigned a0,a1,b0,b1;
        a0=pk2bft(sc[0],sc[1]);   a1=pk2bft(sc[2],sc[3]);
        b0=pk2bft(sc[4],sc[5]);   b1=pk2bft(sc[6],sc[7]);
        plswap(a0,b0); plswap(a1,b1);
        pf[0] = mk8(a0,a1,b0,b1);
        a0=pk2bft(sc[8],sc[9]);   a1=pk2bft(sc[10],sc[11]);
        b0=pk2bft(sc[12],sc[13]); b1=pk2bft(sc[14],sc[15]);
        plswap(a0,b0); plswap(a1,b1);
        pf[1] = mk8(a0,a1,b0,b1);
      }

      // --- PV: O^T[d][q] += V^T-tile x P (kt = this wave's half) ---
      __builtin_amdgcn_s_setprio(1);
      #pragma unroll
      for (int dr=0; dr<2; dr++){
        #pragma unroll
        for (int ks=0; ks<2; ks++){
          short8 va = *(const short8*)(sVc + (size_t)(dr*32 + lq)*64 + ((wk*32 + ks*16 + hi*8) ^ swzr));
          oacc[dr] = __builtin_amdgcn_mfma_f32_32x32x16_bf16(va, pf[ks], oacc[dr], 0,0,0);
        }
      }
      __builtin_amdgcn_s_setprio(0);

      __syncthreads();   // drains vmcnt (stage landed) + all reads of buf done
    } // ss

    // ---- epilogue: combine partials across wk pairs (buf1 region free;
    //      buf0 holds the prefetched next-phase tile during phase 0) ----
    float den = dq.x + dq.y;
    den += __shfl_xor(den, 32, 64);

    float* fb  = (float*)(smem + 8192);     // 16 KB (buf1)
    float* dnp = (float*)(smem + 16384);    // den partials (2 KB region)
    if (wk==1){
      #pragma unroll
      for (int dr=0; dr<2; dr++)
        #pragma unroll
        for (int g=0; g<16; g++)
          fb[wq*2048 + (dr*16+g)*64 + l] = oacc[dr][g];
      dnp[wq*64 + l] = den;
    }
    __syncthreads();
    if (wk==0){
      #pragma unroll
      for (int dr=0; dr<2; dr++)
        #pragma unroll
        for (int g=0; g<16; g++)
          oacc[dr][g] += fb[wq*2048 + (dr*16+g)*64 + l];
      den += dnp[wq*64 + l];
      if (phase==0){
        // q <- (xi K) * CE, as B-frags; share with wk=1 partner via qsh.
        // qsh(wq) placed inside the fb region this wave ALREADY read:
        // wq=0 -> shorts [8192,10240), wq=1 -> shorts [14336,16384)
        float iv = CE_ * __builtin_amdgcn_rcpf(den);
        qf[0] = conv8a(oacc[0], iv);
        qf[1] = conv8b(oacc[0], iv);
        qf[2] = conv8a(oacc[1], iv);
        qf[3] = conv8b(oacc[1], iv);
        unsigned short* qsh = smem + 8192 + wq*6144;
        #pragma unroll
        for (int d=0; d<4; d++)
          *(short8*)(qsh + d*512 + l*8) = qf[d];
      } else {
        float iv = __builtin_amdgcn_rcpf(den);
        // C row = (r&3)+8*(r>>2)+4*hi -> d = g*8 + hi*4 + {0..3}
        unsigned short* Ob = QO + (size_t)(qt*64 + wq*32 + lq)*D_ + h*64 + hi*4;
        #pragma unroll
        for (int g=0; g<4; g++){
          uint2 pk;
          pk.x = pk2bf(oacc[0][4*g+0]*iv, oacc[0][4*g+1]*iv);
          pk.y = pk2bf(oacc[0][4*g+2]*iv, oacc[0][4*g+3]*iv);
          *(uint2*)(Ob + g*8) = pk;
          pk.x = pk2bf(oacc[1][4*g+0]*iv, oacc[1][4*g+1]*iv);
          pk.y = pk2bf(oacc[1][4*g+2]*iv, oacc[1][4*g+3]*iv);
          *(uint2*)(Ob + 32 + g*8) = pk;
        }
      }
    }
    __syncthreads();
    if (phase==0 && wk==1){
      unsigned short* qsh = smem + 8192 + wq*6144;
      #pragma unroll
      for (int d=0; d<4; d++)
        qf[d] = *(const short8*)(qsh + d*512 + l*8);
    }
    __syncthreads();   // qsh reads done before phase-1 staging reuses buf1
  } // phase
}

// ---------------------------------------------------------------------------
extern "C" void kernel_launch(void* const* d_in, const int* in_sizes, int n_in,
                              void* d_out, int out_size, void* d_ws, size_t ws_size,
                              hipStream_t stream){
  const float* data = (const float*)d_in[0];
  const float* g_k  = (const float*)d_in[1];
  const float* b_k  = (const float*)d_in[2];
  const float* g_q  = (const float*)d_in[3];
  const float* b_q  = (const float*)d_in[4];
  const float* g_v  = (const float*)d_in[5];
  const float* b_v  = (const float*)d_in[6];
  const float* Wq   = (const float*)d_in[7];
  const float* bq   = (const float*)d_in[8];
  const float* Wk   = (const float*)d_in[9];
  const float* bk   = (const float*)d_in[10];
  const float* Wv   = (const float*)d_in[11];
  const float* bv   = (const float*)d_in[12];
  const float* Wo   = (const float*)d_in[13];
  const float* bo   = (const float*)d_in[14];
  float* out = (float*)d_out;

  char* ws = (char*)d_ws;
  const size_t MB = (size_t)1<<20;
  unsigned short* q    = (unsigned short*)(ws);
  unsigned short* kb   = (unsigned short*)(ws + 8*MB);
  unsigned short* WT   = (unsigned short*)(ws + 16*MB);
  unsigned short* WTo  = WT + ((size_t)3<<20);
  unsigned short* xhat = (unsigned short*)(ws + 24*MB);
  float*          bfld = (float*)(ws + 32*MB);
  unsigned short* vT   = (unsigned short*)d_out;
  unsigned short* kT   = (unsigned short*)((char*)d_out + 8*MB);

  dim3 gb(256);
  prep_kernel<<<dim3(2096), gb, 0, stream>>>(data,
                                             Wq, Wk, Wv, Wo, g_q, g_k, g_v,
                                             b_q, b_k, b_v, bq, bk, bv,
                                             WT, xhat, bfld);
  gemm_qkv<<<dim3(32,8,3), gb, 0, stream>>>(xhat, WT, bfld, q, kb, kT, vT);
  attn_fused<<<dim3(64, H_), gb, 0, stream>>>(q, kb, kT, vT);
  gemm_out<<<dim3(32,8), gb, 0, stream>>>(q, WTo, bo, out);
}

// Round 5
// 242.892 us; speedup vs baseline: 1.5939x; 1.0481x over previous
//
#include <hip/hip_runtime.h>
#include <hip/hip_bf16.h>

// Problem constants
#define B_  2
#define S_  2048
#define D_  1024
#define H_  16
#define HD_ 64
#define M_  4096   // B_*S_

// Inputs/outputs f32; internal compute bf16 MFMA with f32 accumulation.
// ws (32 MB + 12 KB):
//   [0,8)MB  q bf16 (CE-prescaled via WTq/biasf; attn in-place)
//   [8,16)MB kb bf16
//   [16,24)MB WT bf16: 4 x [1024][1024] ([q CE*g | k g | v g | o plain])
//   [24,32)MB xhat bf16 [4096][1024]  (LN(data), affine folded into WT/biasf)
//   +32MB: biasf f32[3][1024]
// d_out (16 MB f32) as scratch until the final GEMM:
//   [0,8)MB vT bf16 [bh][d][s]   [8,16)MB kT bf16 [bh][d][s]
//
// attn_fused (this round): 2 q-tiles per wave -> every LDS A-frag read
// feeds 2 MFMAs (R4 bottleneck: LDS pipe 164K cyc/CU vs 65K MFMA).
// 128-thread blocks (2 waves = kt-halves), launch_bounds(128,2) ->
// 256-VGPR cap, ~170 used, no spill (R3's failure mode). 4 blocks/CU
// via LDS (33KB). Async double-buffer staging as R4. XCD-aware block
// swizzle: 2 heads per XCD -> K/V working set fits 4MB L2.

typedef __attribute__((ext_vector_type(8))) short short8;
typedef __attribute__((ext_vector_type(4))) float f32x4;
typedef __attribute__((ext_vector_type(2))) float f32x2;
typedef __attribute__((ext_vector_type(16))) float f32x16;

#define CE_ 0.1803368801111204f   // 0.125 * log2(e)

typedef __attribute__((address_space(1))) const unsigned GU;
typedef __attribute__((address_space(3))) unsigned LU;
static __device__ __forceinline__ void glds16(const void* g, void* l){
  __builtin_amdgcn_global_load_lds((GU*)g, (LU*)l, 16, 0, 0);
}

static __device__ __forceinline__ unsigned short f2bfc(float f){
  union{float f; unsigned u;} c; c.f = f;
  return (unsigned short)((c.u + 0x8000u) >> 16);
}
static __device__ __forceinline__ unsigned pk2bf(float a, float b){
  union{float f; unsigned u;} ca, cb; ca.f=a; cb.f=b;
  return __builtin_amdgcn_perm(cb.u + 0x8000u, ca.u + 0x8000u, 0x07060302u);
}
static __device__ __forceinline__ unsigned pk2bft(float a, float b){
  union{float f; unsigned u;} ca, cb; ca.f=a; cb.f=b;
  return __builtin_amdgcn_perm(cb.u, ca.u, 0x07060302u);
}
static __device__ __forceinline__ short8 mk8(unsigned x0, unsigned x1,
                                             unsigned x2, unsigned x3){
  union{ unsigned u[4]; short8 s; } t;
  t.u[0]=x0; t.u[1]=x1; t.u[2]=x2; t.u[3]=x3; return t.s;
}
// v_permlane32_swap_b32: new_x[32:63] = old_y[0:31]; new_y[0:31] = old_x[32:63]
static __device__ __forceinline__ void plswap(unsigned &x, unsigned &y){
  auto r = __builtin_amdgcn_permlane32_swap(x, y, false, false);
  x = (unsigned)r[0]; y = (unsigned)r[1];
}
// convert C-layout f32 rows -> one B-frag (proven R1/R2). a: regs 0..7 / 8..15
static __device__ __forceinline__ short8 conv8a(const f32x16& v, float iv){
  unsigned a0 = pk2bf(v[0]*iv, v[1]*iv);
  unsigned a1 = pk2bf(v[2]*iv, v[3]*iv);
  unsigned b0 = pk2bf(v[4]*iv, v[5]*iv);
  unsigned b1 = pk2bf(v[6]*iv, v[7]*iv);
  plswap(a0,b0); plswap(a1,b1);
  return mk8(a0,a1,b0,b1);
}
static __device__ __forceinline__ short8 conv8b(const f32x16& v, float iv){
  unsigned a0 = pk2bf(v[8]*iv,  v[9]*iv);
  unsigned a1 = pk2bf(v[10]*iv, v[11]*iv);
  unsigned b0 = pk2bf(v[12]*iv, v[13]*iv);
  unsigned b1 = pk2bf(v[14]*iv, v[15]*iv);
  plswap(a0,b0); plswap(a1,b1);
  return mk8(a0,a1,b0,b1);
}

// ---------------------------------------------------------------------------
// Merged prep: [0,1024) wtrans ; [1024,2048) xhat (stats+normalize fused,
// one row per wave) ; [2048,2096) biasfold.
// ---------------------------------------------------------------------------
__global__ __launch_bounds__(256) void prep_kernel(
  const float* __restrict__ data,
  const float* __restrict__ Wq, const float* __restrict__ Wk,
  const float* __restrict__ Wv, const float* __restrict__ Wo,
  const float* __restrict__ gq, const float* __restrict__ gk, const float* __restrict__ gv,
  const float* __restrict__ blq, const float* __restrict__ blk, const float* __restrict__ blv,
  const float* __restrict__ bpq, const float* __restrict__ bpk, const float* __restrict__ bpv,
  unsigned short* __restrict__ WT, unsigned short* __restrict__ xhat,
  float* __restrict__ bf)
{
  __shared__ unsigned short tile[64][72];
  __shared__ float red[4][64];
  int bid = blockIdx.x, t = threadIdx.x;
  if (bid < 1024){
    // --- weight transpose + cast: WT[z][n][k] = scale_z[k] * W_z[k][n] ---
    int z = bid >> 8, rem = bid & 255;
    int k0 = (rem>>4)*64, n0 = (rem&15)*64;
    const float* W = (z==0)?Wq:(z==1)?Wk:(z==2)?Wv:Wo;
    const float* g = (z==0)?gq:(z==1)?gk:(z==2)?gv:(const float*)0;
    unsigned short* out = WT + ((size_t)z<<20);
    {
      int kr = t>>2, c16 = (t&3)*16;
      float gs = g ? g[k0+kr]*((z==0)?CE_:1.0f) : 1.0f;
      const float* src = W + (size_t)(k0+kr)*D_ + n0 + c16;
      float4 w0 = *(const float4*)(src);
      float4 w1 = *(const float4*)(src+4);
      float4 w2 = *(const float4*)(src+8);
      float4 w3 = *(const float4*)(src+12);
      unsigned* tp = (unsigned*)&tile[kr][c16];
      tp[0]=pk2bf(w0.x*gs,w0.y*gs); tp[1]=pk2bf(w0.z*gs,w0.w*gs);
      tp[2]=pk2bf(w1.x*gs,w1.y*gs); tp[3]=pk2bf(w1.z*gs,w1.w*gs);
      tp[4]=pk2bf(w2.x*gs,w2.y*gs); tp[5]=pk2bf(w2.z*gs,w2.w*gs);
      tp[6]=pk2bf(w3.x*gs,w3.y*gs); tp[7]=pk2bf(w3.z*gs,w3.w*gs);
    }
    __syncthreads();
    {
      int nr = t>>2, kc = (t&3)*16;
      union { uint4 v[2]; unsigned short u[16]; } st;
      #pragma unroll
      for (int i=0;i<16;i++) st.u[i] = tile[kc+i][nr];
      unsigned short* dst = out + (size_t)(n0+nr)*D_ + k0 + kc;
      *(uint4*)(dst)     = st.v[0];
      *(uint4*)(dst + 8) = st.v[1];
    }
  } else if (bid < 2048){
    // --- xhat: one row per wave, stats + normalize + bf16 store ---
    int row = (bid-1024)*4 + (t>>6);
    int l = t & 63;
    const float4* xr = (const float4*)(data + (size_t)row*D_);
    float4 v[4];
    float s = 0.f, ss = 0.f;
    #pragma unroll
    for (int i=0;i<4;i++){
      v[i] = xr[l + 64*i];
      s  += v[i].x+v[i].y+v[i].z+v[i].w;
      ss += v[i].x*v[i].x+v[i].y*v[i].y+v[i].z*v[i].z+v[i].w*v[i].w;
    }
    #pragma unroll
    for (int m=1;m<64;m<<=1){ s += __shfl_xor(s, m, 64); ss += __shfl_xor(ss, m, 64); }
    float me = s*(1.0f/D_);
    float var = ss*(1.0f/D_) - me*me;
    float rs = rsqrtf(var + 1e-5f);
    float nm = -me*rs;
    unsigned short* xo = xhat + (size_t)row*D_;
    #pragma unroll
    for (int i=0;i<4;i++){
      uint2 pk;
      pk.x = pk2bf(fmaf(v[i].x,rs,nm), fmaf(v[i].y,rs,nm));
      pk.y = pk2bf(fmaf(v[i].z,rs,nm), fmaf(v[i].w,rs,nm));
      *(uint2*)(xo + 4*l + 256*i) = pk;
    }
  } else {
    // --- folded bias ---
    int idx = bid - 2048;
    int z = idx >> 4, xb = idx & 15;
    const float* W  = (z==0)?Wq:(z==1)?Wk:Wv;
    const float* bl = (z==0)?blq:(z==1)?blk:blv;
    const float* bp = (z==0)?bpq:(z==1)?bpk:bpv;
    int nl = t & 63, kg = t >> 6;
    int n = xb*64 + nl;
    float acc = 0.f;
    for (int k = kg*256; k < (kg+1)*256; k++)
      acc += bl[k] * W[(size_t)k*D_ + n];
    red[kg][nl] = acc;
    __syncthreads();
    if (t < 64){
      int nn = xb*64 + t;
      float v = red[0][t]+red[1][t]+red[2][t]+red[3][t] + bp[nn];
      bf[z*D_ + nn] = (z==0) ? v*CE_ : v;
    }
  }
}

// ---------------------------------------------------------------------------
// Fused QKV GEMM, grid (32,8,3). 128x128 tile. Both tiles via glds width=16
// (A from precomputed bf16 xhat), unpadded stride-32 LDS.
// ---------------------------------------------------------------------------
__global__ __launch_bounds__(256) void gemm_qkv(
  const unsigned short* __restrict__ xhat,
  const unsigned short* __restrict__ WT,
  const float* __restrict__ biasf,
  unsigned short* __restrict__ qv, unsigned short* __restrict__ kb,
  unsigned short* __restrict__ kT, unsigned short* __restrict__ vT)
{
  int z = blockIdx.z;
  const unsigned short* Bt = WT + ((size_t)z<<20);
  const float* bias = biasf + z*D_;
  unsigned short* oN = (z==0)?qv:(z==1)?kb:(unsigned short*)0;
  unsigned short* oT = (z==0)?(unsigned short*)0:(z==1)?kT:vT;

  __shared__ __align__(16) unsigned short As[128*32];
  __shared__ __align__(16) unsigned short Bs[128*32];
  int tid = threadIdx.x, w = tid>>6, l = tid&63;
  int m0 = blockIdx.x*128, n0 = blockIdx.y*128;
  int wr = (w>>1)*64, wc = (w&1)*64;
  int lr = l&15, qd = l>>4;

  const unsigned short* gA = xhat + (size_t)(m0 + w*32 + (l>>2))*D_ + (l&3)*8;
  const unsigned short* gB = Bt   + (size_t)(n0 + w*32 + (l>>2))*D_ + (l&3)*8;
  unsigned short* lA0 = &As[(w*32)*32];
  unsigned short* lA1 = &As[(w*32+16)*32];
  unsigned short* lB0 = &Bs[(w*32)*32];
  unsigned short* lB1 = &Bs[(w*32+16)*32];

  const f32x4 fz = {0.f,0.f,0.f,0.f};
  f32x4 acc[4][4];
  #pragma unroll
  for (int i=0;i<4;i++)
    #pragma unroll
    for (int j=0;j<4;j++) acc[i][j] = fz;

  for (int kk=0; kk<D_; kk+=32){
    __syncthreads();
    glds16(gA + kk,                 lA0);
    glds16(gA + kk + (size_t)16*D_, lA1);
    glds16(gB + kk,                 lB0);
    glds16(gB + kk + (size_t)16*D_, lB1);
    __syncthreads();
    short8 af[4], bfr[4];
    #pragma unroll
    for (int i=0;i<4;i++) af[i]  = *(const short8*)(As + (wr + i*16 + lr)*32 + qd*8);
    #pragma unroll
    for (int j=0;j<4;j++) bfr[j] = *(const short8*)(Bs + (wc + j*16 + lr)*32 + qd*8);
    #pragma unroll
    for (int i=0;i<4;i++)
      #pragma unroll
      for (int j=0;j<4;j++)
        acc[i][j] = __builtin_amdgcn_mfma_f32_16x16x32_bf16(af[i], bfr[j], acc[i][j], 0, 0, 0);
  }

  #pragma unroll
  for (int j=0;j<4;j++){
    int n = n0 + wc + j*16 + lr;
    float bias_n = bias[n];
    #pragma unroll
    for (int i=0;i<4;i++){
      int mb = m0 + wr + i*16 + qd*4;
      float v0 = acc[i][j][0] + bias_n;
      float v1 = acc[i][j][1] + bias_n;
      float v2 = acc[i][j][2] + bias_n;
      float v3 = acc[i][j][3] + bias_n;
      if (oN){
        oN[(size_t)(mb+0)*D_ + n] = f2bfc(v0);
        oN[(size_t)(mb+1)*D_ + n] = f2bfc(v1);
        oN[(size_t)(mb+2)*D_ + n] = f2bfc(v2);
        oN[(size_t)(mb+3)*D_ + n] = f2bfc(v3);
      }
      if (oT){
        int bb = mb >> 11, sI = mb & (S_-1);
        int hh = n >> 6,  dd = n & 63;
        uint2 pk; pk.x = pk2bf(v0, v1); pk.y = pk2bf(v2, v3);
        *(uint2*)(oT + (size_t)((bb*H_ + hh)*HD_ + dd)*S_ + sI) = pk;
      }
    }
  }
}

// ---------------------------------------------------------------------------
// Out-projection: C = A(bf16) @ WTo^T + bo, f32 to d_out. Both tiles via glds.
// ---------------------------------------------------------------------------
__global__ __launch_bounds__(256) void gemm_out(
  const unsigned short* __restrict__ A,
  const unsigned short* __restrict__ Bt,
  const float* __restrict__ bo,
  float* __restrict__ Cf)
{
  __shared__ __align__(16) unsigned short As[128*32];
  __shared__ __align__(16) unsigned short Bs[128*32];
  int tid = threadIdx.x, w = tid>>6, l = tid&63;
  int m0 = blockIdx.x*128, n0 = blockIdx.y*128;
  int wr = (w>>1)*64, wc = (w&1)*64;
  int lr = l&15, qd = l>>4;

  const unsigned short* gA = A  + (size_t)(m0 + w*32 + (l>>2))*D_ + (l&3)*8;
  const unsigned short* gB = Bt + (size_t)(n0 + w*32 + (l>>2))*D_ + (l&3)*8;
  unsigned short* lA0 = &As[(w*32)*32];
  unsigned short* lA1 = &As[(w*32+16)*32];
  unsigned short* lB0 = &Bs[(w*32)*32];
  unsigned short* lB1 = &Bs[(w*32+16)*32];

  const f32x4 fz = {0.f,0.f,0.f,0.f};
  f32x4 acc[4][4];
  #pragma unroll
  for (int i=0;i<4;i++)
    #pragma unroll
    for (int j=0;j<4;j++) acc[i][j] = fz;

  for (int kk=0; kk<D_; kk+=32){
    __syncthreads();
    glds16(gA + kk,                 lA0);
    glds16(gA + kk + (size_t)16*D_, lA1);
    glds16(gB + kk,                 lB0);
    glds16(gB + kk + (size_t)16*D_, lB1);
    __syncthreads();
    short8 af[4], bfr[4];
    #pragma unroll
    for (int i=0;i<4;i++) af[i]  = *(const short8*)(As + (wr + i*16 + lr)*32 + qd*8);
    #pragma unroll
    for (int j=0;j<4;j++) bfr[j] = *(const short8*)(Bs + (wc + j*16 + lr)*32 + qd*8);
    #pragma unroll
    for (int i=0;i<4;i++)
      #pragma unroll
      for (int j=0;j<4;j++)
        acc[i][j] = __builtin_amdgcn_mfma_f32_16x16x32_bf16(af[i], bfr[j], acc[i][j], 0, 0, 0);
  }

  #pragma unroll
  for (int j=0;j<4;j++){
    int n = n0 + wc + j*16 + lr;
    float bias_n = bo[n];
    #pragma unroll
    for (int i=0;i<4;i++){
      int mb = m0 + wr + i*16 + qd*4;
      Cf[(size_t)(mb+0)*D_ + n] = acc[i][j][0] + bias_n;
      Cf[(size_t)(mb+1)*D_ + n] = acc[i][j][1] + bias_n;
      Cf[(size_t)(mb+2)*D_ + n] = acc[i][j][2] + bias_n;
      Cf[(size_t)(mb+3)*D_ + n] = acc[i][j][3] + bias_n;
    }
  }
}

// ---------------------------------------------------------------------------
// Fused double Hopfield attention: 2 q-tiles/wave, 128 threads (2 waves =
// kt-halves of a 64-kt superstep), async double-buffer. Each A-frag read
// feeds 2 MFMAs. Grid (64,16) XCD-swizzled (2 heads per XCD -> L2-fit).
// LDS 33KB: 2x16KB buffers ([sK 64x64][sV 64x64]) + 512B den.
// ---------------------------------------------------------------------------
__global__ __launch_bounds__(128, 2) void attn_fused(
  unsigned short* __restrict__ QO,
  const unsigned short* __restrict__ K,
  const unsigned short* __restrict__ KT,
  const unsigned short* __restrict__ VT)
{
  // XCD-aware bijective swizzle of the 1024-block grid: id = xcd*128+slot
  // -> h = id>>6 (2 heads/XCD), qt = id&63.
  int lin = blockIdx.x + (blockIdx.y << 6);
  int id  = ((lin & 7) << 7) + (lin >> 3);
  int qt = id & 63;              // 0..63 -> 64 q-rows
  int h  = id >> 6;              // 0..15
  int b  = qt >> 5;
  int bh = b*H_ + h;
  int tid = threadIdx.x, w = tid>>6, l = tid&63;
  int lq = l & 31, hi = l >> 5;
  int swzr = (lq & 7) << 3;

  __shared__ __align__(16) unsigned short smem[16640];  // 33 KB
  float* dnp = (float*)(smem + 16384);   // 128 floats den partials

  const f32x16 fz16 = {0.f,0.f,0.f,0.f,0.f,0.f,0.f,0.f,
                       0.f,0.f,0.f,0.f,0.f,0.f,0.f,0.f};

  // ---- initial Q fragments, both q-tiles (B-frag: k = hi*8+i, col = lq) ----
  const unsigned short* Qb = QO + (size_t)(qt*64 + lq)*D_ + h*64;
  short8 qf[2][4];
  #pragma unroll
  for (int qc=0; qc<2; qc++)
    #pragma unroll
    for (int d=0; d<4; d++)
      qf[qc][d] = *(const short8*)(Qb + (size_t)qc*32*D_ + d*16 + hi*8);

  const unsigned short* Khead = K + (size_t)(b*S_)*D_ + h*64;
  const unsigned short* Vh0 = KT + (size_t)bh*HD_*S_;
  const unsigned short* Vh1 = VT + (size_t)bh*HD_*S_;

  // ---- staging geometry (pre-swizzled global sources, linear LDS) ----
  // wave w stages K rows [w*32, w*32+32) and V rows [w*32, +32), 4 glds each
  int lr8 = l>>3;
  int swzs = ((l&7)*8) ^ (lr8*8);
  const unsigned short* gKs  = Khead + (size_t)(w*32 + lr8)*D_ + swzs;
  const unsigned short* gV0s = Vh0 + (size_t)(w*32 + lr8)*S_ + swzs;
  const unsigned short* gV1s = Vh1 + (size_t)(w*32 + lr8)*S_ + swzs;
  int dK = w*2048 + l*8;            // shorts, + buf*8192
  int dV = 4096 + w*2048 + l*8;

  // ---- prologue: stage t=0 into buf0 ----
  #pragma unroll
  for (int j=0;j<4;j++){
    glds16(gKs  + (size_t)j*8*D_, smem + dK + j*512);
    glds16(gV0s + (size_t)j*8*S_, smem + dV + j*512);
  }
  __syncthreads();

  #pragma unroll 1
  for (int phase=0; phase<2; phase++){
    f32x16 oacc[2][2];
    oacc[0][0]=fz16; oacc[0][1]=fz16; oacc[1][0]=fz16; oacc[1][1]=fz16;
    f32x2 dq0 = {0.f,0.f}, dq1 = {0.f,0.f};

    #pragma unroll 1
    for (int ss=0; ss<32; ss++){
      int t = phase*32 + ss;
      // --- stage t+1 into buf (t+1)&1 (skipped on the very last step) ---
      if (t < 63){
        int tn = t + 1;
        int tt = tn & 31;
        unsigned short* bb = smem + ((tn&1) ? 8192 : 0);
        const unsigned short* gk = gKs + (size_t)tt*64*D_;
        const unsigned short* gv = ((tn >= 32) ? gV1s : gV0s) + tt*64;
        #pragma unroll
        for (int j=0;j<4;j++){
          glds16(gk + (size_t)j*8*D_, bb + dK + j*512);
          glds16(gv + (size_t)j*8*S_, bb + dV + j*512);
        }
      }
      __builtin_amdgcn_sched_barrier(0);   // keep stage issue before compute

      const unsigned short* sKc = smem + ((t&1) ? 8192 : 0);
      const unsigned short* sVc = sKc + 4096;

      // --- QK^T on this wave's 32-kt half: S^T[kt][q], 2 q-tiles ---
      f32x16 sc0 = fz16, sc1 = fz16;
      __builtin_amdgcn_s_setprio(1);
      #pragma unroll
      for (int d4=0; d4<4; d4++){
        short8 ka = *(const short8*)(sKc + (size_t)(w*32 + lq)*64 + ((d4*16 + hi*8) ^ swzr));
        sc0 = __builtin_amdgcn_mfma_f32_32x32x16_bf16(ka, qf[0][d4], sc0, 0,0,0);
        sc1 = __builtin_amdgcn_mfma_f32_32x32x16_bf16(ka, qf[1][d4], sc1, 0,0,0);
      }
      __builtin_amdgcn_s_setprio(0);

      // --- exp2 + packed den accumulation (both q-tiles) ---
      #pragma unroll
      for (int i=0;i<16;i++){
        sc0[i] = __builtin_amdgcn_exp2f(sc0[i]);
        sc1[i] = __builtin_amdgcn_exp2f(sc1[i]);
      }
      #pragma unroll
      for (int i=0;i<16;i+=2){
        dq0 += (f32x2){sc0[i], sc0[i+1]};
        dq1 += (f32x2){sc1[i], sc1[i+1]};
      }

      // --- in-register P -> B-frag conversion (T12), both q-tiles ---
      short8 pf0[2], pf1[2];
      {
        unsigned a0,a1,b0,b1;
        a0=pk2bft(sc0[0],sc0[1]);   a1=pk2bft(sc0[2],sc0[3]);
        b0=pk2bft(sc0[4],sc0[5]);   b1=pk2bft(sc0[6],sc0[7]);
        plswap(a0,b0); plswap(a1,b1);
        pf0[0] = mk8(a0,a1,b0,b1);
        a0=pk2bft(sc0[8],sc0[9]);   a1=pk2bft(sc0[10],sc0[11]);
        b0=pk2bft(sc0[12],sc0[13]); b1=pk2bft(sc0[14],sc0[15]);
        plswap(a0,b0); plswap(a1,b1);
        pf0[1] = mk8(a0,a1,b0,b1);
        a0=pk2bft(sc1[0],sc1[1]);   a1=pk2bft(sc1[2],sc1[3]);
        b0=pk2bft(sc1[4],sc1[5]);   b1=pk2bft(sc1[6],sc1[7]);
        plswap(a0,b0); plswap(a1,b1);
        pf1[0] = mk8(a0,a1,b0,b1);
        a0=pk2bft(sc1[8],sc1[9]);   a1=pk2bft(sc1[10],sc1[11]);
        b0=pk2bft(sc1[12],sc1[13]); b1=pk2bft(sc1[14],sc1[15]);
        plswap(a0,b0); plswap(a1,b1);
        pf1[1] = mk8(a0,a1,b0,b1);
      }

      // --- PV: O^T[d][q] += V^T-tile x P; each va feeds both q-tiles ---
      __builtin_amdgcn_s_setprio(1);
      #pragma unroll
      for (int dr=0; dr<2; dr++){
        #pragma unroll
        for (int ks=0; ks<2; ks++){
          short8 va = *(const short8*)(sVc + (size_t)(dr*32 + lq)*64 + ((w*32 + ks*16 + hi*8) ^ swzr));
          oacc[0][dr] = __builtin_amdgcn_mfma_f32_32x32x16_bf16(va, pf0[ks], oacc[0][dr], 0,0,0);
          oacc[1][dr] = __builtin_amdgcn_mfma_f32_32x32x16_bf16(va, pf1[ks], oacc[1][dr], 0,0,0);
        }
      }
      __builtin_amdgcn_s_setprio(0);

      __syncthreads();   // drains vmcnt (stage landed) + all reads of buf done
    } // ss

    // ---- epilogue: combine partials across the 2 waves (buf1 scratch) ----
    float den0 = dq0.x + dq0.y; den0 += __shfl_xor(den0, 32, 64);
    float den1 = dq1.x + dq1.y; den1 += __shfl_xor(den1, 32, 64);

    float* fb = (float*)(smem + 8192);   // 16 KB (buf1; just-read by all)
    if (w==1){
      #pragma unroll
      for (int qc=0; qc<2; qc++)
        #pragma unroll
        for (int dr=0; dr<2; dr++)
          #pragma unroll
          for (int g=0; g<16; g++)
            fb[(qc*32 + dr*16 + g)*64 + l] = oacc[qc][dr][g];
      dnp[l]      = den0;
      dnp[64 + l] = den1;
    }
    __syncthreads();
    if (w==0){
      #pragma unroll
      for (int qc=0; qc<2; qc++)
        #pragma unroll
        for (int dr=0; dr<2; dr++)
          #pragma unroll
          for (int g=0; g<16; g++)
            oacc[qc][dr][g] += fb[(qc*32 + dr*16 + g)*64 + l];
      den0 += dnp[l];
      den1 += dnp[64 + l];
      if (phase==0){
        // q <- (xi K) * CE, as B-frags (in-register); share via qsh (buf1)
        float iv0 = CE_ * __builtin_amdgcn_rcpf(den0);
        float iv1 = CE_ * __builtin_amdgcn_rcpf(den1);
        qf[0][0] = conv8a(oacc[0][0], iv0);
        qf[0][1] = conv8b(oacc[0][0], iv0);
        qf[0][2] = conv8a(oacc[0][1], iv0);
        qf[0][3] = conv8b(oacc[0][1], iv0);
        qf[1][0] = conv8a(oacc[1][0], iv1);
        qf[1][1] = conv8b(oacc[1][0], iv1);
        qf[1][2] = conv8a(oacc[1][1], iv1);
        qf[1][3] = conv8b(oacc[1][1], iv1);
        unsigned short* qsh = smem + 8192;
        #pragma unroll
        for (int qc=0; qc<2; qc++)
          #pragma unroll
          for (int d=0; d<4; d++)
            *(short8*)(qsh + (size_t)(qc*4 + d)*512 + l*8) = qf[qc][d];
      } else {
        float iv0 = __builtin_amdgcn_rcpf(den0);
        float iv1 = __builtin_amdgcn_rcpf(den1);
        // C row = (r&3)+8*(r>>2)+4*hi -> d = dr*32 + g*8 + hi*4 + {0..3}
        #pragma unroll
        for (int qc=0; qc<2; qc++){
          float iv = qc ? iv1 : iv0;
          unsigned short* Ob = QO + (size_t)(qt*64 + qc*32 + lq)*D_ + h*64 + hi*4;
          #pragma unroll
          for (int g=0; g<4; g++){
            uint2 pk;
            pk.x = pk2bf(oacc[qc][0][4*g+0]*iv, oacc[qc][0][4*g+1]*iv);
            pk.y = pk2bf(oacc[qc][0][4*g+2]*iv, oacc[qc][0][4*g+3]*iv);
            *(uint2*)(Ob + g*8) = pk;
            pk.x = pk2bf(oacc[qc][1][4*g+0]*iv, oacc[qc][1][4*g+1]*iv);
            pk.y = pk2bf(oacc[qc][1][4*g+2]*iv, oacc[qc][1][4*g+3]*iv);
            *(uint2*)(Ob + 32 + g*8) = pk;
          }
        }
      }
    }
    __syncthreads();
    if (phase==0 && w==1){
      unsigned short* qsh = smem + 8192;
      #pragma unroll
      for (int qc=0; qc<2; qc++)
        #pragma unroll
        for (int d=0; d<4; d++)
          qf[qc][d] = *(const short8*)(qsh + (size_t)(qc*4 + d)*512 + l*8);
    }
    __syncthreads();   // qsh reads done before phase-1 staging reuses buf1
  } // phase
}

// ---------------------------------------------------------------------------
extern "C" void kernel_launch(void* const* d_in, const int* in_sizes, int n_in,
                              void* d_out, int out_size, void* d_ws, size_t ws_size,
                              hipStream_t stream){
  const float* data = (const float*)d_in[0];
  const float* g_k  = (const float*)d_in[1];
  const float* b_k  = (const float*)d_in[2];
  const float* g_q  = (const float*)d_in[3];
  const float* b_q  = (const float*)d_in[4];
  const float* g_v  = (const float*)d_in[5];
  const float* b_v  = (const float*)d_in[6];
  const float* Wq   = (const float*)d_in[7];
  const float* bq   = (const float*)d_in[8];
  const float* Wk   = (const float*)d_in[9];
  const float* bk   = (const float*)d_in[10];
  const float* Wv   = (const float*)d_in[11];
  const float* bv   = (const float*)d_in[12];
  const float* Wo   = (const float*)d_in[13];
  const float* bo   = (const float*)d_in[14];
  float* out = (float*)d_out;

  char* ws = (char*)d_ws;
  const size_t MB = (size_t)1<<20;
  unsigned short* q    = (unsigned short*)(ws);
  unsigned short* kb   = (unsigned short*)(ws + 8*MB);
  unsigned short* WT   = (unsigned short*)(ws + 16*MB);
  unsigned short* WTo  = WT + ((size_t)3<<20);
  unsigned short* xhat = (unsigned short*)(ws + 24*MB);
  float*          bfld = (float*)(ws + 32*MB);
  unsigned short* vT   = (unsigned short*)d_out;
  unsigned short* kT   = (unsigned short*)((char*)d_out + 8*MB);

  dim3 gb(256);
  prep_kernel<<<dim3(2096), gb, 0, stream>>>(data,
                                             Wq, Wk, Wv, Wo, g_q, g_k, g_v,
                                             b_q, b_k, b_v, bq, bk, bv,
                                             WT, xhat, bfld);
  gemm_qkv<<<dim3(32,8,3), gb, 0, stream>>>(xhat, WT, bfld, q, kb, kT, vT);
  attn_fused<<<dim3(64, H_), dim3(128), 0, stream>>>(q, kb, kT, vT);
  gemm_out<<<dim3(32,8), gb, 0, stream>>>(q, WTo, bo, out);
}